// Round 8
// baseline (37.234 us; speedup 1.0000x reference)
//
#include <hip/hip_runtime.h>

#define NM 1600
#define NG (NM / 4)      // 400 groups of 4 targets
#define NH (NG / 2)      // 200 groups per half-unit
#define NC 91
#define BLOCK 256
#define GRID 1280        // 5 blocks/CU x 256 CUs, fully resident (persistent)

typedef float f32x4 __attribute__((ext_vector_type(4)));
typedef float f32x2 __attribute__((ext_vector_type(2)));

__global__ __launch_bounds__(BLOCK, 5) void matcher_cost_kernel(
    const float* __restrict__ logits,   // [BQ, 91]
    const float* __restrict__ pboxes,   // [BQ, 4] cxcywh
    const int*   __restrict__ tlabels,  // [1600]
    const float* __restrict__ tboxes,   // [1600, 4] cxcywh
    float* __restrict__ out,            // [BQ, 1600]
    int BQ)
{
    // One-time SoA half-width target staging + per-wave c2 rows. ~30.3 KB.
    __shared__ float4 s_cx[NG], s_cy[NG], s_hw[NG], s_hh[NG]; // 25600 B
    __shared__ unsigned s_lab[NG];                            // 1600 B
    __shared__ float s_tab[4][2][NC + 5];                     // 3072 B

    const int tid  = threadIdx.x;
    const int wv   = tid >> 6;
    const int lane = tid & 63;

    // ---- stage targets once ----
    const float4* tb4 = (const float4*)tboxes;
    const int4*   lb4 = (const int4*)tlabels;
    for (int g = tid; g < NG; g += BLOCK) {
        float4 t0 = tb4[4 * g + 0], t1 = tb4[4 * g + 1];
        float4 t2 = tb4[4 * g + 2], t3 = tb4[4 * g + 3];
        s_cx[g] = make_float4(t0.x, t1.x, t2.x, t3.x);
        s_cy[g] = make_float4(t0.y, t1.y, t2.y, t3.y);
        s_hw[g] = make_float4(0.5f * t0.z, 0.5f * t1.z, 0.5f * t2.z, 0.5f * t3.z);
        s_hh[g] = make_float4(0.5f * t0.w, 0.5f * t1.w, 0.5f * t2.w, 0.5f * t3.w);
        int4 vl = lb4[g];
        s_lab[g] = (unsigned)(vl.x & 0xff) | ((unsigned)(vl.y & 0xff) << 8)
                 | ((unsigned)(vl.z & 0xff) << 16) | ((unsigned)(vl.w & 0xff) << 24);
    }
    __syncthreads();
    // ---- no barriers below: each wave is fully independent ----

    const int npair = BQ >> 1;                 // 7200
    const int totw  = (int)gridDim.x * 4;      // 5120
    const int gwid  = (int)blockIdx.x * 4 + wv;
    const f32x2 zero2 = {0.0f, 0.0f};

    for (int u = gwid; u < BQ; u += totw) {
        const int half = (u >= npair) ? 1 : 0;
        const int pair = u - half * npair;

        // softmax for both queries of the pair -> private c2 rows (2 - p)
        #pragma unroll
        for (int k = 0; k < 2; ++k) {
            const int q = 2 * pair + k;
            const float* lrow = logits + (size_t)q * NC;
            float v0 = (lane      < NC) ? lrow[lane]      : -3.4e38f;
            float v1 = (lane + 64 < NC) ? lrow[lane + 64] : -3.4e38f;
            float mx = fmaxf(v0, v1);
            #pragma unroll
            for (int off = 32; off; off >>= 1) mx = fmaxf(mx, __shfl_xor(mx, off));
            float e0 = (lane      < NC) ? __expf(v0 - mx) : 0.0f;
            float e1 = (lane + 64 < NC) ? __expf(v1 - mx) : 0.0f;
            float s = e0 + e1;
            #pragma unroll
            for (int off = 32; off; off >>= 1) s += __shfl_xor(s, off);
            float inv = 1.0f / s;
            if (lane      < NC) s_tab[wv][k][lane]      = 2.0f - e0 * inv;
            if (lane + 64 < NC) s_tab[wv][k][lane + 64] = 2.0f - e1 * inv;
        }

        // query constants (half-width form, f32x2 splats)
        f32x2 qcx[2], qcy[2], qhw[2], qhh[2], qa[2];
        #pragma unroll
        for (int k = 0; k < 2; ++k) {
            float4 pb = ((const float4*)pboxes)[2 * pair + k];
            qcx[k] = (f32x2){pb.x, pb.x};
            qcy[k] = (f32x2){pb.y, pb.y};
            qhw[k] = (f32x2){0.5f * pb.z, 0.5f * pb.z};
            qhh[k] = (f32x2){0.5f * pb.w, 0.5f * pb.w};
            float a = pb.z * pb.w;
            qa[k]  = (f32x2){a, a};
        }

        // sweep this unit's half of the target groups
        const int gbeg = half * NH;
        for (int g = gbeg + lane; g < gbeg + NH; g += 64) {
            float4 vcx = s_cx[g], vcy = s_cy[g], vhw = s_hw[g], vhh = s_hh[g];
            unsigned labw = s_lab[g];
            f32x2 tcx[2] = {{vcx.x, vcx.y}, {vcx.z, vcx.w}};
            f32x2 tcy[2] = {{vcy.x, vcy.y}, {vcy.z, vcy.w}};
            f32x2 thw[2] = {{vhw.x, vhw.y}, {vhw.z, vhw.w}};
            f32x2 thh[2] = {{vhh.x, vhh.y}, {vhh.z, vhh.w}};
            f32x2 ta[2];
            #pragma unroll
            for (int h = 0; h < 2; ++h) ta[h] = 4.0f * (thw[h] * thh[h]);

            #pragma unroll
            for (int k = 0; k < 2; ++k) {
                const float* tab = s_tab[wv][k];
                f32x2 rr2[2];
                #pragma unroll
                for (int h = 0; h < 2; ++h) {
                    f32x2 adx = __builtin_elementwise_abs(qcx[k] - tcx[h]);
                    f32x2 ady = __builtin_elementwise_abs(qcy[k] - tcy[h]);
                    f32x2 adw = __builtin_elementwise_abs(qhw[k] - thw[h]);
                    f32x2 adh = __builtin_elementwise_abs(qhh[k] - thh[h]);
                    f32x2 A = adx + ady;
                    f32x2 B = adw + adh;
                    f32x2 sx = qhw[k] + thw[h];
                    f32x2 sy = qhh[k] + thh[h];
                    f32x2 mxx = __builtin_elementwise_max(adx, adw);
                    f32x2 mxy = __builtin_elementwise_max(ady, adh);
                    f32x2 iw = __builtin_elementwise_max(sx - mxx, zero2);
                    f32x2 ih = __builtin_elementwise_max(sy - mxy, zero2);
                    f32x2 inter = iw * ih;
                    f32x2 earea = (sx + mxx) * (sy + mxy);
                    f32x2 uni = (qa[k] + ta[h]) - inter;
                    f32x2 ue = uni * earea;
                    f32x2 rr = {__builtin_amdgcn_rcpf(ue[0]),
                                __builtin_amdgcn_rcpf(ue[1])};
                    f32x2 X = (uni * uni + inter * earea) * rr;
                    f32x2 c2 = {tab[(labw >> (16 * h)) & 0xff],
                                tab[(labw >> (16 * h + 8)) & 0xff]};
                    rr2[h] = -2.0f * X + (5.0f * A + (10.0f * B + c2));
                }
                f32x4 r4 = {rr2[0][0], rr2[0][1], rr2[1][0], rr2[1][1]};
                __builtin_nontemporal_store(r4,
                    (f32x4*)(out + (size_t)(2 * pair + k) * NM) + g);
            }
        }
    }
}

extern "C" void kernel_launch(void* const* d_in, const int* in_sizes, int n_in,
                              void* d_out, int out_size, void* d_ws, size_t ws_size,
                              hipStream_t stream) {
    const float* logits  = (const float*)d_in[0];
    const float* pboxes  = (const float*)d_in[1];
    const int*   tlabels = (const int*)d_in[2];
    const float* tboxes  = (const float*)d_in[3];
    float* out = (float*)d_out;

    const int BQ = in_sizes[1] / 4;   // 14400
    matcher_cost_kernel<<<GRID, BLOCK, 0, stream>>>(logits, pboxes, tlabels,
                                                    tboxes, out, BQ);
}

// Round 9
// 32.561 us; speedup vs baseline: 1.1435x; 1.1435x over previous
//
#include <hip/hip_runtime.h>

#define QT 8             // queries per block (2 per wave)
#define NM 1600
#define NG (NM / 4)      // 400 groups of 4 targets
#define NC 91
#define BLOCK 256

typedef float f32x4 __attribute__((ext_vector_type(4)));
typedef float f32x2 __attribute__((ext_vector_type(2)));

__global__ __launch_bounds__(BLOCK, 5) void matcher_cost_kernel(
    const float* __restrict__ logits,   // [BQ, 91]
    const float* __restrict__ pboxes,   // [BQ, 4] cxcywh
    const int*   __restrict__ tlabels,  // [1600]
    const float* __restrict__ tboxes,   // [1600, 4] cxcywh
    float* __restrict__ out)            // [BQ, 1600]
{
    // SoA half-width staging + packed-u8 labels + per-block (2 - prob) table.
    __shared__ float4 s_cx[NG], s_cy[NG], s_hw[NG], s_hh[NG]; // 25600 B
    __shared__ unsigned s_lab[NG];                            // 1600 B
    __shared__ float s_c2[QT][NC + 1];                        // 2944 B

    const int tid  = threadIdx.x;
    const int wv   = tid >> 6;      // wave 0..3
    const int lane = tid & 63;
    const int q0   = blockIdx.x * QT;

    // ---- stage targets AoS -> SoA (half-widths), labels -> packed u8 ----
    const float4* tb4 = (const float4*)tboxes;
    const int4*   lb4 = (const int4*)tlabels;
    for (int g = tid; g < NG; g += BLOCK) {
        float4 t0 = tb4[4 * g + 0], t1 = tb4[4 * g + 1];
        float4 t2 = tb4[4 * g + 2], t3 = tb4[4 * g + 3];
        s_cx[g] = make_float4(t0.x, t1.x, t2.x, t3.x);
        s_cy[g] = make_float4(t0.y, t1.y, t2.y, t3.y);
        s_hw[g] = make_float4(0.5f * t0.z, 0.5f * t1.z, 0.5f * t2.z, 0.5f * t3.z);
        s_hh[g] = make_float4(0.5f * t0.w, 0.5f * t1.w, 0.5f * t2.w, 0.5f * t3.w);
        int4 vl = lb4[g];
        s_lab[g] = (unsigned)(vl.x & 0xff) | ((unsigned)(vl.y & 0xff) << 8)
                 | ((unsigned)(vl.z & 0xff) << 16) | ((unsigned)(vl.w & 0xff) << 24);
    }

    // ---- softmax: wave wv computes queries q0+2*wv, q0+2*wv+1; stores 2-p ----
    #pragma unroll
    for (int k = 0; k < 2; ++k) {
        const int ql = 2 * wv + k;
        const float* lrow = logits + (size_t)(q0 + ql) * NC;
        float v0 = (lane      < NC) ? lrow[lane]      : -3.4e38f;
        float v1 = (lane + 64 < NC) ? lrow[lane + 64] : -3.4e38f;
        float mx = fmaxf(v0, v1);
        #pragma unroll
        for (int off = 32; off; off >>= 1) mx = fmaxf(mx, __shfl_xor(mx, off));
        float e0 = (lane      < NC) ? __expf(v0 - mx) : 0.0f;
        float e1 = (lane + 64 < NC) ? __expf(v1 - mx) : 0.0f;
        float s = e0 + e1;
        #pragma unroll
        for (int off = 32; off; off >>= 1) s += __shfl_xor(s, off);
        float inv = 1.0f / s;
        if (lane      < NC) s_c2[ql][lane]      = 2.0f - e0 * inv;
        if (lane + 64 < NC) s_c2[ql][lane + 64] = 2.0f - e1 * inv;
    }

    // ---- query constants as f32x2 splats (half-width form) ----
    f32x2 qcx[2], qcy[2], qhw[2], qhh[2], qa[2];
    #pragma unroll
    for (int k = 0; k < 2; ++k) {
        float4 pb = ((const float4*)pboxes)[q0 + 2 * wv + k];
        qcx[k] = (f32x2){pb.x, pb.x};
        qcy[k] = (f32x2){pb.y, pb.y};
        qhw[k] = (f32x2){0.5f * pb.z, 0.5f * pb.z};
        qhh[k] = (f32x2){0.5f * pb.w, 0.5f * pb.w};
        float a = pb.z * pb.w;
        qa[k]  = (f32x2){a, a};
    }

    __syncthreads();

    const f32x2 zero2 = {0.0f, 0.0f};

    // ---- sweep: packed f32x2 math, 2 target-pairs per op, 2 queries/wave ----
    #pragma unroll 2
    for (int g = lane; g < NG; g += 64) {
        float4 vcx = s_cx[g], vcy = s_cy[g], vhw = s_hw[g], vhh = s_hh[g];
        unsigned labw = s_lab[g];
        f32x2 tcx[2] = {{vcx.x, vcx.y}, {vcx.z, vcx.w}};
        f32x2 tcy[2] = {{vcy.x, vcy.y}, {vcy.z, vcy.w}};
        f32x2 thw[2] = {{vhw.x, vhw.y}, {vhw.z, vhw.w}};
        f32x2 thh[2] = {{vhh.x, vhh.y}, {vhh.z, vhh.w}};
        f32x2 ta[2];
        #pragma unroll
        for (int h = 0; h < 2; ++h) ta[h] = 4.0f * (thw[h] * thh[h]);

        #pragma unroll
        for (int k = 0; k < 2; ++k) {
            const int ql = 2 * wv + k;
            const float* tab = s_c2[ql];
            f32x2 rr2[2];
            #pragma unroll
            for (int h = 0; h < 2; ++h) {
                f32x2 adx = __builtin_elementwise_abs(qcx[k] - tcx[h]);
                f32x2 ady = __builtin_elementwise_abs(qcy[k] - tcy[h]);
                f32x2 adw = __builtin_elementwise_abs(qhw[k] - thw[h]);
                f32x2 adh = __builtin_elementwise_abs(qhh[k] - thh[h]);
                f32x2 A = adx + ady;            // |dcx|+|dcy|
                f32x2 B = adw + adh;            // (|dw|+|dh|)/2
                f32x2 sx = qhw[k] + thw[h];
                f32x2 sy = qhh[k] + thh[h];
                f32x2 mxx = __builtin_elementwise_max(adx, adw);
                f32x2 mxy = __builtin_elementwise_max(ady, adh);
                f32x2 iw = __builtin_elementwise_max(sx - mxx, zero2);
                f32x2 ih = __builtin_elementwise_max(sy - mxy, zero2);
                f32x2 inter = iw * ih;
                f32x2 earea = (sx + mxx) * (sy + mxy);
                f32x2 uni = (qa[k] + ta[h]) - inter;
                f32x2 ue = uni * earea;
                f32x2 rr = {__builtin_amdgcn_rcpf(ue[0]),
                            __builtin_amdgcn_rcpf(ue[1])};
                f32x2 X = (uni * uni + inter * earea) * rr;
                f32x2 c2 = {tab[(labw >> (16 * h)) & 0xff],
                            tab[(labw >> (16 * h + 8)) & 0xff]};
                rr2[h] = -2.0f * X + (5.0f * A + (10.0f * B + c2));
            }
            // regular (L2-allocating) store — A/B vs NT from R7
            f32x4 r4 = {rr2[0][0], rr2[0][1], rr2[1][0], rr2[1][1]};
            *((f32x4*)(out + (size_t)(q0 + ql) * NM) + g) = r4;
        }
    }
}

extern "C" void kernel_launch(void* const* d_in, const int* in_sizes, int n_in,
                              void* d_out, int out_size, void* d_ws, size_t ws_size,
                              hipStream_t stream) {
    const float* logits  = (const float*)d_in[0];
    const float* pboxes  = (const float*)d_in[1];
    const int*   tlabels = (const int*)d_in[2];
    const float* tboxes  = (const float*)d_in[3];
    float* out = (float*)d_out;

    const int BQ = in_sizes[1] / 4;   // 14400
    const int grid = BQ / QT;         // 1800
    matcher_cost_kernel<<<grid, BLOCK, 0, stream>>>(logits, pboxes, tlabels, tboxes, out);
}